// Round 1
// baseline (322.007 us; speedup 1.0000x reference)
//
#include <hip/hip_runtime.h>

// SkipGram negative-sampling loss, MI355X (gfx950).
// Inputs (setup_inputs order):
//   d_in[0] max_stroke_len (int scalar) -- hardcoded 20
//   d_in[1] n_sample       (int scalar) -- hardcoded 5
//   d_in[2] pos_u  int32 [B, L]
//   d_in[3] pos_v  int32 [B, L]
//   d_in[4] neg_v  int32 [B, S, L]
//   d_in[5] u_emb  f32   [200000, 128]
//   d_in[6] v_emb  f32   [100000, 128]
// Output: f32 scalar  -mean_b( logsig(eu.ev) + sum_s logsig(-(nv_s.eu)) )

constexpr int BATCH = 16384;
constexpr int LEN   = 20;
constexpr int NS    = 5;
constexpr int DIM   = 128;

__device__ __forceinline__ float log_sigmoid(float x) {
    // stable: min(x,0) - log1p(exp(-|x|))
    return fminf(x, 0.0f) - log1pf(expf(-fabsf(x)));
}

__device__ __forceinline__ void acc4(float4& a, const float4 b) {
    a.x += b.x; a.y += b.y; a.z += b.z; a.w += b.w;
}

// sum with the partner half-wave (lane ^ 32): both halves end with full sum
__device__ __forceinline__ float4 combine_halves(float4 v) {
    float4 r;
    r.x = v.x + __shfl_xor(v.x, 32, 64);
    r.y = v.y + __shfl_xor(v.y, 32, 64);
    r.z = v.z + __shfl_xor(v.z, 32, 64);
    r.w = v.w + __shfl_xor(v.w, 32, 64);
    return r;
}

__device__ __forceinline__ float dot4(const float4 a, const float4 b) {
    return a.x*b.x + a.y*b.y + a.z*b.z + a.w*b.w;
}

// reduce across the 32 lanes of each half-wave (quads 0..31). After
// combine_halves the two halves carry identical data, so each half's
// 32-lane reduction independently yields the full dot product.
__device__ __forceinline__ float half_reduce(float v) {
    v += __shfl_xor(v, 16, 64);
    v += __shfl_xor(v, 8, 64);
    v += __shfl_xor(v, 4, 64);
    v += __shfl_xor(v, 2, 64);
    v += __shfl_xor(v, 1, 64);
    return v;
}

__global__ __launch_bounds__(64) void sg_main(
    const int* __restrict__ pos_u, const int* __restrict__ pos_v,
    const int* __restrict__ neg_v, const float* __restrict__ u_emb,
    const float* __restrict__ v_emb, float* __restrict__ partials)
{
    const int b    = blockIdx.x;
    const int t    = threadIdx.x;   // 0..63
    const int half = t >> 5;        // which half-wave: handles rows l%2==half
    const int q    = t & 31;        // quad index: dims [4q, 4q+4)

    __shared__ int sidx[2*LEN + NS*LEN];   // 140 indices for this batch elem

    if (t < LEN)                sidx[t] = pos_u[b*LEN + t];
    else if (t < 2*LEN)         sidx[t] = pos_v[b*LEN + (t - LEN)];
    for (int i = t; i < NS*LEN; i += 64) sidx[2*LEN + i] = neg_v[b*NS*LEN + i];
    __syncthreads();

    float4 su = {0.f,0.f,0.f,0.f};
    float4 sv = {0.f,0.f,0.f,0.f};
    float4 sn[NS];
    #pragma unroll
    for (int s = 0; s < NS; ++s) sn[s] = {0.f,0.f,0.f,0.f};

    // pos_u rows: each half-wave takes every other row (2 rows / wave-load)
    #pragma unroll
    for (int k = 0; k < LEN/2; ++k) {
        const int l = 2*k + half;
        acc4(su, *(reinterpret_cast<const float4*>(u_emb + (size_t)sidx[l]*DIM) + q));
    }
    #pragma unroll
    for (int k = 0; k < LEN/2; ++k) {
        const int l = 2*k + half;
        acc4(sv, *(reinterpret_cast<const float4*>(v_emb + (size_t)sidx[LEN + l]*DIM) + q));
    }
    #pragma unroll
    for (int s = 0; s < NS; ++s) {
        #pragma unroll
        for (int k = 0; k < LEN/2; ++k) {
            const int l = 2*k + half;
            acc4(sn[s], *(reinterpret_cast<const float4*>(
                              v_emb + (size_t)sidx[2*LEN + s*LEN + l]*DIM) + q));
        }
    }

    // full row-sums in every lane
    const float4 eu = combine_halves(su);
    const float4 ev = combine_halves(sv);

    constexpr float inv_LL = 1.0f / (float(LEN) * float(LEN));

    // positive score: (su_sum . sv_sum) / L^2
    float c_pos = half_reduce(dot4(eu, ev)) * inv_LL;

    float loss = log_sigmoid(c_pos);
    #pragma unroll
    for (int s = 0; s < NS; ++s) {
        const float4 nv = combine_halves(sn[s]);
        const float c_neg = half_reduce(dot4(nv, eu)) * inv_LL;
        loss += log_sigmoid(-c_neg);   // neg_emb_v is negated mean
    }

    if (t == 0) partials[b] = loss;
}

__global__ __launch_bounds__(256) void sg_reduce(
    const float* __restrict__ partials, float* __restrict__ out)
{
    const int t = threadIdx.x;
    float acc = 0.f;
    for (int i = t; i < BATCH; i += 256) acc += partials[i];
    #pragma unroll
    for (int m = 32; m >= 1; m >>= 1) acc += __shfl_xor(acc, m, 64);
    __shared__ float sh[4];
    if ((t & 63) == 0) sh[t >> 6] = acc;
    __syncthreads();
    if (t == 0) out[0] = -(sh[0] + sh[1] + sh[2] + sh[3]) * (1.0f / float(BATCH));
}

extern "C" void kernel_launch(void* const* d_in, const int* in_sizes, int n_in,
                              void* d_out, int out_size, void* d_ws, size_t ws_size,
                              hipStream_t stream) {
    const int*   pos_u = (const int*)d_in[2];
    const int*   pos_v = (const int*)d_in[3];
    const int*   neg_v = (const int*)d_in[4];
    const float* u_emb = (const float*)d_in[5];
    const float* v_emb = (const float*)d_in[6];
    float*       out   = (float*)d_out;
    float*       partials = (float*)d_ws;   // BATCH floats = 64 KB

    sg_main<<<BATCH, 64, 0, stream>>>(pos_u, pos_v, neg_v, u_emb, v_emb, partials);
    sg_reduce<<<1, 256, 0, stream>>>(partials, out);
}